// Round 5
// baseline (293.012 us; speedup 1.0000x reference)
//
#include <hip/hip_runtime.h>
#include <stdint.h>

typedef __attribute__((ext_vector_type(4)))  int   intx4;
typedef __attribute__((ext_vector_type(8)))  int   intx8;
typedef __attribute__((ext_vector_type(16))) float floatx16;

#define GLL16(gp, lp)                                                               \
    __builtin_amdgcn_global_load_lds((const __attribute__((address_space(1))) unsigned int*)(gp), \
                                     (__attribute__((address_space(3))) unsigned int*)(lp), 16, 0, 0)
#define GLL4(gp, lp)                                                                \
    __builtin_amdgcn_global_load_lds((const __attribute__((address_space(1))) unsigned int*)(gp), \
                                     (__attribute__((address_space(3))) unsigned int*)(lp), 4, 0, 0)

// wave-local pipeline sync: previous chunk's 10 loads done, current 10 in flight
#define WAITV10 asm volatile("s_waitcnt vmcnt(10)" ::: "memory")
#define WAITV0  asm volatile("s_waitcnt vmcnt(0)"  ::: "memory")

// ---------------------------------------------------------------------------
// Kernel 1: quantize x -> packed e2m1 nibbles + e8m0 codes (natural [m][kb]).
// Thread = 8 consecutive floats; 4 consecutive lanes = one 32-elem MX block.
// ---------------------------------------------------------------------------
__device__ __forceinline__ uint32_t enc1(float xv, float inv) {
    float a = fminf(fabsf(xv) * inv, 6.0f);
    // RTE onto e2m1 grid {0,.5,1,1.5,2,3,4,6} -> code 0..7 (ties-to-even == ref)
    int e;
    if (a < 2.0f)      e = (int)rintf(a + a);
    else if (a < 4.0f) e = (int)rintf(a) + 2;
    else               e = (int)rintf(a * 0.5f) + 4;
    return (uint32_t)e | ((__float_as_uint(xv) >> 28) & 8u);
}

__global__ __launch_bounds__(256) void quant_x_kernel(const float* __restrict__ x,
                                                      uint32_t* __restrict__ xq,
                                                      uint8_t* __restrict__ xs) {
    int t = blockIdx.x * 256 + threadIdx.x;          // 8-float group index
    const float4* src = (const float4*)(x + (size_t)t * 8);
    float4 v0 = src[0], v1 = src[1];
    float mx = fmaxf(fmaxf(fmaxf(fabsf(v0.x), fabsf(v0.y)), fmaxf(fabsf(v0.z), fabsf(v0.w))),
                     fmaxf(fmaxf(fabsf(v1.x), fabsf(v1.y)), fmaxf(fabsf(v1.z), fabsf(v1.w))));
    mx = fmaxf(mx, __shfl_xor(mx, 1, 64));
    mx = fmaxf(mx, __shfl_xor(mx, 2, 64));
    // FLOOR e8m0 code = exp_field - 2, clamped >= 1 (scale >= 2^-126, ref clamp)
    unsigned ef = __float_as_uint(mx) >> 23;
    unsigned code = (ef < 3u) ? 1u : (ef - 2u);
    float inv = __uint_as_float((254u - code) << 23);   // exact 2^(127-code)

    uint32_t w =  enc1(v0.x, inv)        | (enc1(v0.y, inv) << 4)
               | (enc1(v0.z, inv) << 8)  | (enc1(v0.w, inv) << 12)
               | (enc1(v1.x, inv) << 16) | (enc1(v1.y, inv) << 20)
               | (enc1(v1.z, inv) << 24) | (enc1(v1.w, inv) << 28);
    xq[t] = w;
    if ((threadIdx.x & 3) == 0) xs[t >> 2] = (uint8_t)code;
}

// ---------------------------------------------------------------------------
// Kernel 2: densify (setup stores one byte per int32 for packed w and scales)
// ---------------------------------------------------------------------------
__global__ __launch_bounds__(256) void repack_kernel(const int* __restrict__ wp,
                                                     const int* __restrict__ wsc,
                                                     uint32_t* __restrict__ wrep,
                                                     uint32_t* __restrict__ wscb,
                                                     int n4w, int n4s) {
    int t = blockIdx.x * 256 + threadIdx.x;
    if (t < n4w) {
        int4 p = ((const int4*)wp)[t];
        wrep[t] = (uint32_t)(p.x & 0xFF) | ((uint32_t)(p.y & 0xFF) << 8)
                | ((uint32_t)(p.z & 0xFF) << 16) | ((uint32_t)(p.w & 0xFF) << 24);
    } else if (t - n4w < n4s) {
        int u = t - n4w;
        int4 p = ((const int4*)wsc)[u];
        wscb[u] = (uint32_t)(p.x & 0xFF) | ((uint32_t)(p.y & 0xFF) << 8)
                | ((uint32_t)(p.z & 0xFF) << 16) | ((uint32_t)(p.w & 0xFF) << 24);
    }
}

// ---------------------------------------------------------------------------
// Kernel 3: MXFP4 GEMM, barrier-free wave-private pipeline.
// Block = 4 waves (2x2), block tile 128x128, wave tile 64x64 =
// 2x2 v_mfma_scale_f32_32x32x64_f8f6f4 (fmt 4 = fp4). BK=128 (64 B/row).
// Each wave double-buffers its own A/B/scale tiles in a PRIVATE LDS region:
// no __syncthreads anywhere; pipeline sync is s_waitcnt vmcnt(10) so the
// next chunk's 10 GLL loads stay in flight during compute (AITER pattern).
// LDS stored in fragment-read order -> stage dest and read addr are both
// base + lane*16 -> conflict-free, no swizzle.
//   region layout (per wave, per buffer, 8704 B):
//     [0,4096)    A data: off = ((s*2+mt)*64 + h*32 + row)*16
//                 holds A row (mt*32+row), k-piece kp=2s+h (16 B = 1 MX block)
//     [4096,8192) B data, same form
//     [8192,8448) A scales: off = r*4 + kp
//     [8448,8704) B scales
// ---------------------------------------------------------------------------
__global__ __launch_bounds__(256, 2) void gemm_mx_kernel(const uint8_t* __restrict__ Apk,
                                                         const uint8_t* __restrict__ Bpk,
                                                         const uint8_t* __restrict__ As,
                                                         const uint8_t* __restrict__ Bs,
                                                         float* __restrict__ C,
                                                         int M, int N, int K) {
    __shared__ __align__(16) uint8_t lds[4][2][8704];

    const int tid = threadIdx.x;
    const int wave = tid >> 6;
    const int lane = tid & 63;
    const int row = lane & 31;
    const int h = lane >> 5;
    const int bm0 = blockIdx.y << 7;
    const int bn0 = blockIdx.x << 7;
    const int wm = (wave >> 1) << 6;              // 0 / 64
    const int wn = (wave & 1) << 6;
    const int Kb = K >> 1;                        // 2048 packed bytes per row
    const int kbpr = K >> 5;                      // 128 scale bytes per row

    // per-g (g = s*2+mt) staged source row/piece for this lane
    const uint8_t* Agp[4];
    const uint8_t* Bgp[4];
#pragma unroll
    for (int g = 0; g < 4; ++g) {
        const int s = g >> 1, mt = g & 1;
        const int r = mt * 32 + row;              // local row 0..63
        const int kp = 2 * s + h;                 // k-piece 0..3
        Agp[g] = Apk + (size_t)(bm0 + wm + r) * Kb + kp * 16;
        Bgp[g] = Bpk + (size_t)(bn0 + wn + r) * Kb + kp * 16;
    }
    const uint8_t* Asp = As + (size_t)(bm0 + wm + lane) * kbpr;   // 4 B per chunk
    const uint8_t* Bsp = Bs + (size_t)(bn0 + wn + lane) * kbpr;

    uint8_t* reg0 = lds[wave][0];
    uint8_t* reg1 = lds[wave][1];

    floatx16 acc[2][2];
#pragma unroll
    for (int a = 0; a < 2; ++a)
#pragma unroll
        for (int b = 0; b < 2; ++b)
#pragma unroll
            for (int r = 0; r < 16; ++r) acc[a][b][r] = 0.f;

    const int nchunk = K >> 7;                    // 32

    // prologue: stage chunk 0 into buffer 0 (10 loads)
#pragma unroll
    for (int g = 0; g < 4; ++g) {
        GLL16(Agp[g], reg0 + (g * 64 + lane) * 16);
        GLL16(Bgp[g], reg0 + 4096 + (g * 64 + lane) * 16);
    }
    GLL4(Asp, reg0 + 8192 + lane * 4);
    GLL4(Bsp, reg0 + 8448 + lane * 4);

    for (int c = 0; c < nchunk; ++c) {
        uint8_t* cur = (c & 1) ? reg1 : reg0;
        uint8_t* nxt = (c & 1) ? reg0 : reg1;
        if (c + 1 < nchunk) {
            const size_t koff = (size_t)(c + 1) * 64;
#pragma unroll
            for (int g = 0; g < 4; ++g) {
                GLL16(Agp[g] + koff, nxt + (g * 64 + lane) * 16);
                GLL16(Bgp[g] + koff, nxt + 4096 + (g * 64 + lane) * 16);
            }
            GLL4(Asp + (c + 1) * 4, nxt + 8192 + lane * 4);
            GLL4(Bsp + (c + 1) * 4, nxt + 8448 + lane * 4);
            WAITV10;                              // chunk c done; c+1 in flight
        } else {
            WAITV0;                               // last chunk: drain
        }

#pragma unroll
        for (int s = 0; s < 2; ++s) {
            intx4 a4[2], b4[2];
            int sa[2], sb[2];
            const int kp = 2 * s + h;
#pragma unroll
            for (int mt = 0; mt < 2; ++mt) {
                a4[mt] = *(const intx4*)(cur + ((s * 2 + mt) * 64 + lane) * 16);
                sa[mt] = cur[8192 + (mt * 32 + row) * 4 + kp];
            }
#pragma unroll
            for (int nt = 0; nt < 2; ++nt) {
                b4[nt] = *(const intx4*)(cur + 4096 + ((s * 2 + nt) * 64 + lane) * 16);
                sb[nt] = cur[8448 + (nt * 32 + row) * 4 + kp];
            }
#pragma unroll
            for (int mt = 0; mt < 2; ++mt)
#pragma unroll
                for (int nt = 0; nt < 2; ++nt) {
                    intx8 a8 = {a4[mt][0], a4[mt][1], a4[mt][2], a4[mt][3], 0, 0, 0, 0};
                    intx8 b8 = {b4[nt][0], b4[nt][1], b4[nt][2], b4[nt][3], 0, 0, 0, 0};
                    acc[mt][nt] = __builtin_amdgcn_mfma_scale_f32_32x32x64_f8f6f4(
                        a8, b8, acc[mt][nt], 4, 4, 0, sa[mt], 0, sb[nt]);
                }
        }
    }

    // C/D layout (32x32): col = lane&31, row = (reg&3) + 8*(reg>>2) + 4*(lane>>5)
#pragma unroll
    for (int mt = 0; mt < 2; ++mt)
#pragma unroll
        for (int nt = 0; nt < 2; ++nt) {
            const int col = bn0 + wn + nt * 32 + row;
#pragma unroll
            for (int g = 0; g < 4; ++g) {
                const int rw = bm0 + wm + mt * 32 + 8 * g + 4 * h;
#pragma unroll
                for (int q = 0; q < 4; ++q)
                    C[(size_t)(rw + q) * N + col] = acc[mt][nt][4 * g + q];
            }
        }
}

// ---------------------------------------------------------------------------
extern "C" void kernel_launch(void* const* d_in, const int* in_sizes, int n_in,
                              void* d_out, int out_size, void* d_ws, size_t ws_size,
                              hipStream_t stream) {
    const float* x = (const float*)d_in[0];
    const int* wp = (const int*)d_in[1];
    const int* wsc = (const int*)d_in[2];
    float* out = (float*)d_out;

    const int K = 4096;
    const int M = in_sizes[0] / K;            // 4096
    const int N = (in_sizes[1] * 2) / K;      // 4096
    const int kbpr = K / 32;                  // 128
    const int npack = N * K / 2;
    const int nsc = N * kbpr;

    uint32_t* xq   = (uint32_t*)d_ws;                                   // 8 MiB
    uint8_t*  xs   = (uint8_t*)d_ws + (size_t)M * K / 2;                // 512 KiB
    uint32_t* wrep = (uint32_t*)(xs + (size_t)M * kbpr);                // 8 MiB
    uint8_t*  wscb = (uint8_t*)wrep + (size_t)npack;                    // 512 KiB

    quant_x_kernel<<<(M * K / 8) / 256, 256, 0, stream>>>(x, xq, xs);

    int n4w = npack / 4, n4s = nsc / 4;
    repack_kernel<<<(n4w + n4s + 255) / 256, 256, 0, stream>>>(wp, wsc, wrep,
                                                               (uint32_t*)wscb, n4w, n4s);

    dim3 grid(N / 128, M / 128);
    gemm_mx_kernel<<<grid, 256, 0, stream>>>((const uint8_t*)xq, (const uint8_t*)wrep,
                                             xs, wscb, out, M, N, K);
}